// Round 1
// baseline (141.972 us; speedup 1.0000x reference)
//
#include <hip/hip_runtime.h>

// SoftProjection: B=4, N=8192 points, M=4096 queries, F=64 features, K=16 NN.
// Per query: exact 16 smallest ||q-p||^2, softmax(-d2/sigma), weighted sums of
// points (3) and features (64).
//
// Structure:
//   transpose_feat : (B,F,N) -> (B,N,F) in d_ws for coalesced gathers
//   soft_proj      : 256 blocks x 1024 thr; block = 64 consecutive queries of
//                    one batch; wave = 4 queries; point cloud chunked via LDS.
// Top-16 scheme: pass A per-lane min over 128 pts -> 16th-smallest of 64 lane
// minima = provable upper bound t on d2_(16); pass B collects survivors
// d2<=t (~19 expected, cap 48), exact rank-select by (d2,idx).

#define BB 4
#define NN 8192
#define MM 4096
#define FF 64
#define KK 16
#define CHUNK 2048
#define NCHUNK 4
#define QPW 4
#define WAVES 16
#define QPB 64
#define SCAP 48

__global__ __launch_bounds__(256) void transpose_feat(const float* __restrict__ pf,
                                                      float* __restrict__ pfT) {
    __shared__ float tile[64][65];
    const int b = blockIdx.y;
    const int n0 = blockIdx.x * 64;
    const int t = threadIdx.x;
    const int n = t & 63, fq = t >> 6;
#pragma unroll
    for (int i = 0; i < 16; ++i) {
        int f = fq * 16 + i;
        tile[f][n] = pf[(size_t)b * FF * NN + (size_t)f * NN + n0 + n];
    }
    __syncthreads();
    const int f2 = t & 63, nq = t >> 6;
#pragma unroll
    for (int i = 0; i < 16; ++i) {
        int nn = nq * 16 + i;
        pfT[(size_t)b * NN * FF + (size_t)(n0 + nn) * FF + f2] = tile[f2][nn];
    }
}

// identical distance expression everywhere (explicit fmaf => deterministic)
#define D2EXPR(PX, PY, PZ, Q)                                         \
    ({ float dx_ = (PX) - qx[Q], dy_ = (PY) - qy[Q], dz_ = (PZ) - qz[Q]; \
       fmaf(dx_, dx_, fmaf(dy_, dy_, dz_ * dz_)); })

#define SCAN_PT(PX, PY, PZ)                      \
    do {                                         \
        _Pragma("unroll")                        \
        for (int q = 0; q < QPW; ++q) {          \
            float d2_ = D2EXPR(PX, PY, PZ, q);   \
            mn[q] = fminf(mn[q], d2_);           \
        }                                        \
    } while (0)

#define PASSB_PT(PX, PY, PZ, PIDX)                                   \
    do {                                                             \
        _Pragma("unroll")                                            \
        for (int q = 0; q < QPW; ++q) {                              \
            float d2_ = D2EXPR(PX, PY, PZ, q);                       \
            if (d2_ <= thr[q]) {                                     \
                int pos_ = atomicAdd(&s_cnt[wave * QPW + q], 1);     \
                if (pos_ < SCAP) {                                   \
                    s_surv_d2[(wave * QPW + q) * SCAP + pos_] = d2_; \
                    s_surv_idx[(wave * QPW + q) * SCAP + pos_] = (PIDX); \
                }                                                    \
            }                                                        \
        }                                                            \
    } while (0)

#define LOAD_CHUNK(C)                                                          \
    do {                                                                       \
        for (int j_ = t; j_ < 3 * CHUNK / 4; j_ += 1024) {                     \
            int arr_ = j_ >> 9;                                                \
            int off_ = j_ & 511;                                               \
            float4 v_ = *reinterpret_cast<const float4*>(pcb + arr_ * NN +     \
                                                         (C) * CHUNK + off_ * 4); \
            *reinterpret_cast<float4*>(s_pts + arr_ * CHUNK + off_ * 4) = v_;  \
        }                                                                      \
    } while (0)

__global__ __launch_bounds__(1024) void soft_proj_kernel(
    const float* __restrict__ pc, const float* __restrict__ qc,
    const float* __restrict__ pf, const float* __restrict__ pfT,
    const float* __restrict__ temp, float* __restrict__ out, int useT) {
    __shared__ __align__(16) float s_pts[3 * CHUNK];              // 24 KB
    __shared__ __align__(16) float s_pool[WAVES * QPW * SCAP * 2]; // 24 KB: survivors, later out-stage
    __shared__ int s_cnt[WAVES * QPW];
    __shared__ float s_sel_d2[WAVES * QPW * KK];
    __shared__ int s_sel_idx[WAVES * QPW * KK];

    const int bid = blockIdx.x;
    const int b = bid >> 6;
    const int m0 = (bid & 63) * QPB;
    const int t = threadIdx.x;
    const int wave = t >> 6;
    const int lane = t & 63;

    const float* pcb = pc + (size_t)b * 3 * NN;
    const int mbase = m0 + wave * QPW;

    float qx[QPW], qy[QPW], qz[QPW];
#pragma unroll
    for (int q = 0; q < QPW; ++q) {
        int m = mbase + q;
        qx[q] = qc[(size_t)b * 3 * MM + m];
        qy[q] = qc[(size_t)b * 3 * MM + MM + m];
        qz[q] = qc[(size_t)b * 3 * MM + 2 * MM + m];
    }

    float mn[QPW];
#pragma unroll
    for (int q = 0; q < QPW; ++q) mn[q] = 3.0e38f;

    // ---------------- pass A: per-lane min over this lane's 128 points ------
    for (int c = 0; c < NCHUNK; ++c) {
        __syncthreads();
        LOAD_CHUNK(c);
        __syncthreads();
#pragma unroll
        for (int i = 0; i < CHUNK / 256; ++i) {
            int o = i * 256 + lane * 4;
            float4 x4 = *reinterpret_cast<const float4*>(s_pts + o);
            float4 y4 = *reinterpret_cast<const float4*>(s_pts + CHUNK + o);
            float4 z4 = *reinterpret_cast<const float4*>(s_pts + 2 * CHUNK + o);
            SCAN_PT(x4.x, y4.x, z4.x);
            SCAN_PT(x4.y, y4.y, z4.y);
            SCAN_PT(x4.z, y4.z, z4.z);
            SCAN_PT(x4.w, y4.w, z4.w);
        }
    }

    // ------------- threshold: 16th-smallest of the 64 lane minima -----------
    float thr[QPW];
    {
        int rank[QPW] = {0, 0, 0, 0};
        for (int j = 0; j < 64; ++j) {
#pragma unroll
            for (int q = 0; q < QPW; ++q) {
                float mj = __shfl(mn[q], j, 64);
                rank[q] += (mj < mn[q] || (mj == mn[q] && j < lane)) ? 1 : 0;
            }
        }
#pragma unroll
        for (int q = 0; q < QPW; ++q) {
            unsigned long long bal = __ballot(rank[q] == 15);
            int src = __ffsll((unsigned long long)bal) - 1;
            thr[q] = __shfl(mn[q], src, 64);
        }
    }

    if (lane < QPW) s_cnt[wave * QPW + lane] = 0;

    float* s_surv_d2 = s_pool;
    int* s_surv_idx = (int*)(s_pool + WAVES * QPW * SCAP);

    // ---------------- pass B: collect survivors d2 <= t ---------------------
    for (int c = 0; c < NCHUNK; ++c) {
        __syncthreads();
        LOAD_CHUNK(c);
        __syncthreads();
#pragma unroll
        for (int i = 0; i < CHUNK / 256; ++i) {
            int o = i * 256 + lane * 4;
            float4 x4 = *reinterpret_cast<const float4*>(s_pts + o);
            float4 y4 = *reinterpret_cast<const float4*>(s_pts + CHUNK + o);
            float4 z4 = *reinterpret_cast<const float4*>(s_pts + 2 * CHUNK + o);
            int gb = c * CHUNK + o;
            PASSB_PT(x4.x, y4.x, z4.x, gb + 0);
            PASSB_PT(x4.y, y4.y, z4.y, gb + 1);
            PASSB_PT(x4.z, y4.z, z4.z, gb + 2);
            PASSB_PT(x4.w, y4.w, z4.w, gb + 3);
        }
    }
    __syncthreads();

    // ------------- exact select: rank survivors by (d2, idx) ----------------
#pragma unroll
    for (int q = 0; q < QPW; ++q) {
        int wq = wave * QPW + q;
        int cnt = s_cnt[wq];
        if (cnt > SCAP) cnt = SCAP;
        if (lane < cnt) {
            float dv = s_surv_d2[wq * SCAP + lane];
            int iv = s_surv_idx[wq * SCAP + lane];
            int rank = 0;
            for (int j = 0; j < cnt; ++j) {
                float dj = s_surv_d2[wq * SCAP + j];
                int ij = s_surv_idx[wq * SCAP + j];
                rank += (dj < dv || (dj == dv && ij < iv)) ? 1 : 0;
            }
            if (rank < KK) {
                s_sel_d2[wq * KK + rank] = dv;
                s_sel_idx[wq * KK + rank] = iv;
            }
        }
    }
    __syncthreads();  // survivors dead beyond this point; s_pool becomes out-stage

    // ---------------- softmax + gather + accumulate -------------------------
    float* stage = s_pool;  // [67 rows][65 cols]: rows 0..63 feat, 64..66 proj
    float tval = temp[0];
    float sigma = fmaxf(tval * tval, 1.0e-4f);
    float inv_sigma = 1.0f / sigma;
    const float* pfTb = pfT + (size_t)b * NN * FF;
    const float* pfb = pf + (size_t)b * FF * NN;

#pragma unroll
    for (int q = 0; q < QPW; ++q) {
        int wq = wave * QPW + q;
        int qm = wq & 63;  // column 0..63 within block
        float dk[KK];
        int ik[KK];
#pragma unroll
        for (int k = 0; k < KK; ++k) {
            dk[k] = s_sel_d2[wq * KK + k];
            ik[k] = __builtin_amdgcn_readfirstlane(s_sel_idx[wq * KK + k]);
        }
        float dmin = dk[0];
#pragma unroll
        for (int k = 1; k < KK; ++k) dmin = fminf(dmin, dk[k]);
        float ek[KK];
        float ssum = 0.f;
#pragma unroll
        for (int k = 0; k < KK; ++k) {
            ek[k] = __expf((dmin - dk[k]) * inv_sigma);
            ssum += ek[k];
        }
        float rs = 1.0f / ssum;

        // features: lane == feature index; 16 coalesced 256B gathers
        float fv[KK];
        if (useT) {
#pragma unroll
            for (int k = 0; k < KK; ++k) fv[k] = pfTb[(size_t)ik[k] * FF + lane];
        } else {
#pragma unroll
            for (int k = 0; k < KK; ++k) fv[k] = pfb[(size_t)lane * NN + ik[k]];
        }
        float acc = 0.f;
#pragma unroll
        for (int k = 0; k < KK; ++k) acc = fmaf(ek[k], fv[k], acc);
        stage[lane * 65 + qm] = acc * rs;

        // projected points: lane k<16 loads coords of its selected point
        float px = 0.f, py = 0.f, pz = 0.f;
        if (lane < KK) {
            float dd = s_sel_d2[wq * KK + lane];
            int ii = s_sel_idx[wq * KK + lane];
            float e = __expf((dmin - dd) * inv_sigma);
            px = pcb[ii] * e;
            py = pcb[NN + ii] * e;
            pz = pcb[2 * NN + ii] * e;
        }
#pragma unroll
        for (int off = 1; off < KK; off <<= 1) {
            px += __shfl_xor(px, off, 64);
            py += __shfl_xor(py, off, 64);
            pz += __shfl_xor(pz, off, 64);
        }
        if (lane == 0) {
            stage[(64 + 0) * 65 + qm] = px * rs;
            stage[(64 + 1) * 65 + qm] = py * rs;
            stage[(64 + 2) * 65 + qm] = pz * rs;
        }
    }
    __syncthreads();

    // ---------------- coalesced write-out -----------------------------------
    const size_t featOff = (size_t)BB * 3 * MM;
    for (int j = t; j < 67 * 64; j += 1024) {
        int row = j >> 6, col = j & 63;
        float v = stage[row * 65 + col];
        int m = m0 + col;
        if (row < 64)
            out[featOff + (size_t)b * FF * MM + (size_t)row * MM + m] = v;
        else
            out[(size_t)b * 3 * MM + (size_t)(row - 64) * MM + m] = v;
    }
}

extern "C" void kernel_launch(void* const* d_in, const int* in_sizes, int n_in,
                              void* d_out, int out_size, void* d_ws, size_t ws_size,
                              hipStream_t stream) {
    (void)in_sizes; (void)n_in; (void)out_size;
    const float* pc = (const float*)d_in[0];
    const float* qc = (const float*)d_in[1];
    const float* pf = (const float*)d_in[2];
    const float* temp = (const float*)d_in[3];
    float* out = (float*)d_out;
    float* pfT = (float*)d_ws;
    const size_t needT = (size_t)BB * NN * FF * sizeof(float);  // 8 MB
    int useT = (ws_size >= needT && d_ws != nullptr) ? 1 : 0;

    if (useT) {
        hipLaunchKernelGGL(transpose_feat, dim3(NN / 64, BB), dim3(256), 0, stream,
                           pf, pfT);
    }
    hipLaunchKernelGGL(soft_proj_kernel, dim3((BB * MM) / QPB), dim3(1024), 0,
                       stream, pc, qc, pf, pfT, temp, out, useT);
}

// Round 2
// 131.915 us; speedup vs baseline: 1.0762x; 1.0762x over previous
//
#include <hip/hip_runtime.h>

// SoftProjection: B=4, N=8192 points, M=4096 queries, F=64 features, K=16 NN.
// R2: expanded-form selection metric val = |p|^2 - 2 q.p (3 fma + min per pair,
// ps staged in LDS), QPW=8 via wave-pairs (waves w / w+8 share 8 queries, each
// scans half the points). Threshold t = max of each wave's 8th-smallest lane
// minimum (radix/ballot select) -- provable upper bound on the true 16th NN.
// Pass B collects survivors val<=t (E~20, cap 54), exact rank by (val,idx).
// Epilogue recomputes exact direct-form d2 for softmax (matches reference).

#define BB 4
#define NN 8192
#define MM 4096
#define FF 64
#define KK 16
#define CHUNK 2048
#define NCHUNK 4
#define QPW 8
#define QPB 64
#define SCAP 54
#define NTHR 1024

__global__ __launch_bounds__(256) void transpose_feat(const float* __restrict__ pf,
                                                      float* __restrict__ pfT) {
    __shared__ float tile[64][65];
    const int b = blockIdx.y;
    const int n0 = blockIdx.x * 64;
    const int t = threadIdx.x;
    const int n = t & 63, fq = t >> 6;
#pragma unroll
    for (int i = 0; i < 16; ++i) {
        int f = fq * 16 + i;
        tile[f][n] = pf[(size_t)b * FF * NN + (size_t)f * NN + n0 + n];
    }
    __syncthreads();
    const int f2 = t & 63, nq = t >> 6;
#pragma unroll
    for (int i = 0; i < 16; ++i) {
        int nn2 = nq * 16 + i;
        pfT[(size_t)b * NN * FF + (size_t)(n0 + nn2) * FF + f2] = tile[f2][nn2];
    }
}

__device__ __forceinline__ unsigned mapf(float f) {
    unsigned u = __float_as_uint(f);
    return (u & 0x80000000u) ? ~u : (u | 0x80000000u);
}
__device__ __forceinline__ float unmapf(unsigned k) {
    return (k & 0x80000000u) ? __uint_as_float(k ^ 0x80000000u)
                             : __uint_as_float(~k);
}

// stage chunk C of point cloud into LDS: x, y, z, ps=|p|^2 (512 threads)
#define STAGE(C)                                                            \
    do {                                                                    \
        if (t < CHUNK / 4) {                                                \
            int base_ = (C)*CHUNK + t * 4;                                  \
            float4 x4_ = *(const float4*)(pcb + base_);                     \
            float4 y4_ = *(const float4*)(pcb + NN + base_);                \
            float4 z4_ = *(const float4*)(pcb + 2 * NN + base_);            \
            *(float4*)(s_pts + t * 4) = x4_;                                \
            *(float4*)(s_pts + CHUNK + t * 4) = y4_;                        \
            *(float4*)(s_pts + 2 * CHUNK + t * 4) = z4_;                    \
            float4 p4_;                                                     \
            p4_.x = fmaf(x4_.x, x4_.x, fmaf(y4_.x, y4_.x, z4_.x * z4_.x));  \
            p4_.y = fmaf(x4_.y, x4_.y, fmaf(y4_.y, y4_.y, z4_.y * z4_.y));  \
            p4_.z = fmaf(x4_.z, x4_.z, fmaf(y4_.z, y4_.z, z4_.z * z4_.z));  \
            p4_.w = fmaf(x4_.w, x4_.w, fmaf(y4_.w, y4_.w, z4_.w * z4_.w));  \
            *(float4*)(s_pts + 3 * CHUNK + t * 4) = p4_;                    \
        }                                                                   \
    } while (0)

// identical val expression in both passes (explicit fmaf => bit-deterministic)
#define VAL(X, Y, Z, PS, Q) \
    fmaf((X), qx2[Q], fmaf((Y), qy2[Q], fmaf((Z), qz2[Q], (PS))))

#define PUSH(WQ, V, I)                                          \
    do {                                                        \
        int pos_ = atomicAdd(&s_cnt[WQ], 1);                    \
        if (pos_ < SCAP) {                                      \
            s_surv[((WQ)*SCAP + pos_) * 2] = (V);               \
            s_surv[((WQ)*SCAP + pos_) * 2 + 1] = __int_as_float(I); \
        }                                                       \
    } while (0)

__global__ __launch_bounds__(NTHR, 4) void soft_proj_kernel(
    const float* __restrict__ pc, const float* __restrict__ qc,
    const float* __restrict__ pf, const float* __restrict__ pfT,
    const float* __restrict__ temp, float* __restrict__ out, int useT) {
    __shared__ __align__(16) float s_pts[4 * CHUNK];        // 32768 B
    __shared__ __align__(16) float s_surv[QPB * SCAP * 2];  // 27648 B (val,idx)
    __shared__ int s_cnt[QPB];                              // 256 B
    __shared__ int s_sel[QPB * KK];                         // 4096 B
    __shared__ float s_thr[2 * QPB];                        // 512 B  => 65280 B

    const int bid = blockIdx.x;
    const int b = bid >> 6;
    const int m0 = (bid & 63) * QPB;
    const int t = threadIdx.x;
    const int wave = t >> 6;
    const int lane = t & 63;
    const int pairIdx = wave & 7;
    const int half = wave >> 3;

    const float* pcb = pc + (size_t)b * 3 * NN;
    const float* qcb = qc + (size_t)b * 3 * MM;

    // scan-phase query constants: -2*q
    float qx2[QPW], qy2[QPW], qz2[QPW];
#pragma unroll
    for (int q = 0; q < QPW; ++q) {
        int m = m0 + pairIdx * QPW + q;
        qx2[q] = -2.0f * qcb[m];
        qy2[q] = -2.0f * qcb[MM + m];
        qz2[q] = -2.0f * qcb[2 * MM + m];
    }

    float mn[QPW];
#pragma unroll
    for (int q = 0; q < QPW; ++q) mn[q] = 3.0e38f;

    // ---------------- pass A: per-lane min of val over 64 points ------------
    for (int c = 0; c < NCHUNK; ++c) {
        __syncthreads();
        STAGE(c);
        __syncthreads();
        const int ob = half * 1024 + lane * 4;
#pragma unroll
        for (int g = 0; g < 4; ++g) {
            int oo = ob + g * 256;
            float4 x4 = *(const float4*)(s_pts + oo);
            float4 y4 = *(const float4*)(s_pts + CHUNK + oo);
            float4 z4 = *(const float4*)(s_pts + 2 * CHUNK + oo);
            float4 p4 = *(const float4*)(s_pts + 3 * CHUNK + oo);
#pragma unroll
            for (int q = 0; q < QPW; ++q) {
                float v0 = VAL(x4.x, y4.x, z4.x, p4.x, q);
                float v1 = VAL(x4.y, y4.y, z4.y, p4.y, q);
                float v2 = VAL(x4.z, y4.z, z4.z, p4.z, q);
                float v3 = VAL(x4.w, y4.w, z4.w, p4.w, q);
                mn[q] = fminf(mn[q], fminf(fminf(v0, v1), fminf(v2, v3)));
            }
        }
    }

    // ---- per-wave radix select: 8th-smallest of 64 lane minima (per query) --
    float thrv[QPW];
#pragma unroll
    for (int q = 0; q < QPW; ++q) {
        unsigned key = mapf(mn[q]);
        unsigned res = 0u;
        for (int bb = 31; bb >= 8; --bb) {
            unsigned cand = res | (1u << bb);
            unsigned long long bal = __ballot(key < cand);
            int c2 = __popcll(bal);
            if (c2 < 8) res = cand;  // 8th smallest has this bit set
        }
        thrv[q] = unmapf(res | 0xFFu);  // upper bound on 8th smallest
    }
    if (lane == 0) {
#pragma unroll
        for (int q = 0; q < QPW; ++q)
            s_thr[half * QPB + pairIdx * QPW + q] = thrv[q];
    }
    if (t < QPB) s_cnt[t] = 0;
    __syncthreads();
    // t = max(tA8, tB8): >=8 points <= t in each half => >=16 total => valid
    // upper bound on the true 16th-smallest val.
#pragma unroll
    for (int q = 0; q < QPW; ++q)
        thrv[q] = fmaxf(s_thr[pairIdx * QPW + q], s_thr[QPB + pairIdx * QPW + q]);

    // ---------------- pass B: collect survivors val <= t --------------------
    for (int c = 0; c < NCHUNK; ++c) {
        __syncthreads();
        STAGE(c);
        __syncthreads();
        const int ob = half * 1024 + lane * 4;
#pragma unroll
        for (int g = 0; g < 4; ++g) {
            int oo = ob + g * 256;
            float4 x4 = *(const float4*)(s_pts + oo);
            float4 y4 = *(const float4*)(s_pts + CHUNK + oo);
            float4 z4 = *(const float4*)(s_pts + 2 * CHUNK + oo);
            float4 p4 = *(const float4*)(s_pts + 3 * CHUNK + oo);
            int gi = c * CHUNK + oo;
#pragma unroll
            for (int q = 0; q < QPW; ++q) {
                int wqq = pairIdx * QPW + q;
                float v0 = VAL(x4.x, y4.x, z4.x, p4.x, q);
                float v1 = VAL(x4.y, y4.y, z4.y, p4.y, q);
                float v2 = VAL(x4.z, y4.z, z4.z, p4.z, q);
                float v3 = VAL(x4.w, y4.w, z4.w, p4.w, q);
                if (v0 <= thrv[q]) PUSH(wqq, v0, gi + 0);
                if (v1 <= thrv[q]) PUSH(wqq, v1, gi + 1);
                if (v2 <= thrv[q]) PUSH(wqq, v2, gi + 2);
                if (v3 <= thrv[q]) PUSH(wqq, v3, gi + 3);
            }
        }
    }
    __syncthreads();

    // ------------- exact select: rank survivors by (val, idx) ---------------
#pragma unroll
    for (int qq = 0; qq < 4; ++qq) {
        int wq = wave * 4 + qq;
        int cnt = s_cnt[wq];
        cnt = __builtin_amdgcn_readfirstlane(cnt);
        if (cnt > SCAP) cnt = SCAP;
        bool valid = lane < cnt;
        float mv = 0.f;
        int mi = 0;
        if (valid) {
            mv = s_surv[(wq * SCAP + lane) * 2];
            mi = __float_as_int(s_surv[(wq * SCAP + lane) * 2 + 1]);
        }
        int rank = 0;
        for (int j = 0; j < cnt; ++j) {
            float vj = s_surv[(wq * SCAP + j) * 2];
            int ij = __float_as_int(s_surv[(wq * SCAP + j) * 2 + 1]);
            if (valid && (vj < mv || (vj == mv && ij < mi))) rank++;
        }
        if (valid && rank < KK) s_sel[wq * KK + rank] = mi;
    }
    __syncthreads();  // survivors dead; s_surv becomes the output stage

    // ---------------- softmax + gather + accumulate -------------------------
    float* stage = s_surv;  // [67 rows][65 cols]
    float tval = temp[0];
    float sigma = fmaxf(tval * tval, 1.0e-4f);
    float inv_sigma = 1.0f / sigma;
    const float* pfTb = pfT + (size_t)b * NN * FF;
    const float* pfb = pf + (size_t)b * FF * NN;

#pragma unroll
    for (int qq = 0; qq < 4; ++qq) {
        int wq = wave * 4 + qq;
        int m = m0 + wq;
        float qxe = qcb[m], qye = qcb[MM + m], qze = qcb[2 * MM + m];
        int ik[KK];
        float dk[KK];
#pragma unroll
        for (int k = 0; k < KK; ++k) {
            int ii = __builtin_amdgcn_readfirstlane(s_sel[wq * KK + k]);
            ik[k] = ii;
            float px = pcb[ii], py = pcb[NN + ii], pz = pcb[2 * NN + ii];
            float dx = px - qxe, dy = py - qye, dz = pz - qze;
            dk[k] = fmaf(dx, dx, fmaf(dy, dy, dz * dz));  // exact direct form
        }
        float dmin = dk[0];
#pragma unroll
        for (int k = 1; k < KK; ++k) dmin = fminf(dmin, dk[k]);
        float ssum = 0.f, facc = 0.f, sx = 0.f, sy = 0.f, sz = 0.f;
#pragma unroll
        for (int k = 0; k < KK; ++k) {
            float e = __expf((dmin - dk[k]) * inv_sigma);
            ssum += e;
            float px = pcb[ik[k]], py = pcb[NN + ik[k]], pz = pcb[2 * NN + ik[k]];
            sx = fmaf(e, px, sx);
            sy = fmaf(e, py, sy);
            sz = fmaf(e, pz, sz);
            float fv = useT ? pfTb[(size_t)ik[k] * FF + lane]
                            : pfb[(size_t)lane * NN + ik[k]];
            facc = fmaf(e, fv, facc);
        }
        float rs = 1.0f / ssum;
        stage[lane * 65 + wq] = facc * rs;
        if (lane == 0) {
            stage[64 * 65 + wq] = sx * rs;
            stage[65 * 65 + wq] = sy * rs;
            stage[66 * 65 + wq] = sz * rs;
        }
    }
    __syncthreads();

    // ---------------- coalesced write-out -----------------------------------
    const size_t featOff = (size_t)BB * 3 * MM;
    for (int j = t; j < 67 * 64; j += NTHR) {
        int row = j >> 6, col = j & 63;
        float v = stage[row * 65 + col];
        int m = m0 + col;
        if (row < 64)
            out[featOff + (size_t)b * FF * MM + (size_t)row * MM + m] = v;
        else
            out[(size_t)b * 3 * MM + (size_t)(row - 64) * MM + m] = v;
    }
}

extern "C" void kernel_launch(void* const* d_in, const int* in_sizes, int n_in,
                              void* d_out, int out_size, void* d_ws, size_t ws_size,
                              hipStream_t stream) {
    (void)in_sizes; (void)n_in; (void)out_size;
    const float* pc = (const float*)d_in[0];
    const float* qc = (const float*)d_in[1];
    const float* pf = (const float*)d_in[2];
    const float* temp = (const float*)d_in[3];
    float* out = (float*)d_out;
    float* pfT = (float*)d_ws;
    const size_t needT = (size_t)BB * NN * FF * sizeof(float);  // 8 MB
    int useT = (ws_size >= needT && d_ws != nullptr) ? 1 : 0;

    if (useT) {
        hipLaunchKernelGGL(transpose_feat, dim3(NN / 64, BB), dim3(256), 0, stream,
                           pf, pfT);
    }
    hipLaunchKernelGGL(soft_proj_kernel, dim3((BB * MM) / QPB), dim3(NTHR), 0,
                       stream, pc, qc, pf, pfT, temp, out, useT);
}